// Round 14
// baseline (932.802 us; speedup 1.0000x reference)
//
#include <hip/hip_runtime.h>
#include <hip/hip_bf16.h>
#include <cstdint>
#include <cstddef>

#define ALPHA 0.1f
#define K_ITERS 10
#define NPART 8

typedef __attribute__((ext_vector_type(8))) short bf16x8;
typedef __attribute__((ext_vector_type(4))) float f32x4;
typedef __attribute__((ext_vector_type(4))) unsigned int u32x4;

#define U15INV (1.0f / 32767.0f)

__device__ __forceinline__ unsigned short f2bf(float f) {
    unsigned int u = __float_as_uint(f);
    u += 0x7fffu + ((u >> 16) & 1u);          // RNE
    return (unsigned short)(u >> 16);
}
__device__ __forceinline__ float bflo(unsigned int u) {
    return __uint_as_float(u << 16);
}
__device__ __forceinline__ float bfhi(unsigned int u) {
    return __uint_as_float(u & 0xffff0000u);
}
__device__ __forceinline__ unsigned int pack2(float a, float b) {
    return (unsigned int)f2bf(a) | ((unsigned int)f2bf(b) << 16);
}
__device__ __forceinline__ unsigned int u15q(float w) {   // w in [0,1]
    return (unsigned int)(w * 32767.0f + 0.5f);
}
__device__ __forceinline__ int xcd_id() {
    unsigned int x;
    asm volatile("s_getreg_b32 %0, hwreg(20, 0, 32)" : "=s"(x));   // HW_REG_XCC_ID (gfx950)
    return (int)(x & (NPART - 1));
}

// ---------------- helper kernels ----------------

// combined setup: zero cnt partitions, flag, and csr buffer
__global__ __launch_bounds__(256) void setup_k(int* cntp, unsigned int* cs, int* flag,
                                               int ncnt, int ncs) {
    int i = blockIdx.x * 256 + threadIdx.x;
    if (i == 0) *flag = 0;
    if (i < ncnt) cntp[i] = 0;
    if (i < ncs) cs[i] = 0;    // src=0, w=0 -> contributes 0
}

// Detect whether edge_index buffer is int64 (values in [0,N) when read as ll) or int32.
__global__ void detect_idx_k(const void* ei, int* flag, int E_, int N_) {
    int tid = threadIdx.x;
    const long long* p = (const long long*)ei;
    int bad = 0;
    int lim = (E_ < 4096) ? E_ : 4096;
    for (int i = tid; i < lim; i += 256) {
        long long v = p[i];
        if (v < 0 || v >= (long long)N_) bad = 1;
    }
    if (bad) atomicOr(flag, 1);   // 1 => buffer is int32
}

// decode indices, sigmoid-masked w (unorm15), XCD-local histogram rank.
// Streaming traffic (ei/ew reads, epack store) is NON-TEMPORAL so the 400KB/XCD
// histogram slab stays L2-resident and the workgroup-scope atomic stays local.
// epack u64: r:17 | c:17<<17 | w15<<34 | part:3<<49 | rank:12<<52
__global__ __launch_bounds__(256) void prep_edges_k(const void* ei, const float* ew,
                                                    unsigned long long* epack, int* cntp,
                                                    const int* flag, int E_, int N_) {
    int e = blockIdx.x * 256 + threadIdx.x;
    if (e >= E_) return;
    int is32 = *flag;
    unsigned long long r, c;
    if (is32) {
        const int* p = (const int*)ei;
        r = (unsigned long long)(unsigned int)__builtin_nontemporal_load(&p[e]);
        c = (unsigned long long)(unsigned int)__builtin_nontemporal_load(&p[(size_t)E_ + e]);
    } else {
        const long long* p = (const long long*)ei;
        r = (unsigned long long)__builtin_nontemporal_load(&p[e]);
        c = (unsigned long long)__builtin_nontemporal_load(&p[(size_t)E_ + e]);
    }
    float t = __builtin_nontemporal_load(&ew[e]);
    float wv = (fabsf(t) > 0.0f) ? 1.0f / (1.0f + expf(-t)) : 0.0f;
    unsigned long long part = (unsigned long long)xcd_id();
    unsigned long long rk = (unsigned long long)(unsigned int)
        __hip_atomic_fetch_add(&cntp[(size_t)part * N_ + (int)c], 1,
                               __ATOMIC_RELAXED, __HIP_MEMORY_SCOPE_WORKGROUP);
    unsigned long long v = r | (c << 17) | ((unsigned long long)u15q(wv) << 34)
                             | (part << 49) | (rk << 52);
    __builtin_nontemporal_store(v, &epack[e]);
}

// per-node: prefix over NPART partition counts -> pofs; padded total -> cnt8
__global__ __launch_bounds__(256) void combine_k(const int* cntp, int* pofs, int* cnt8, int N_) {
    int i = blockIdx.x * 256 + threadIdx.x;
    if (i >= N_) return;
    int s = 0;
    #pragma unroll
    for (int p = 0; p < NPART; ++p) {
        size_t idx = (size_t)p * N_ + i;
        int v = cntp[idx];
        pofs[idx] = s;
        s += v;
    }
    cnt8[i] = (s + 7) & ~7;   // pad rows to multiple of 8
}

// hierarchical exclusive scan of cnt8 -> rowstart
__global__ __launch_bounds__(256) void scan1_k(const int* cnt, int* bsum, int N_) {
    __shared__ int sm[256];
    int t = threadIdx.x, i = blockIdx.x * 256 + t;
    sm[t] = (i < N_) ? cnt[i] : 0;
    __syncthreads();
    for (int off = 128; off; off >>= 1) {
        if (t < off) sm[t] += sm[t + off];
        __syncthreads();
    }
    if (t == 0) bsum[blockIdx.x] = sm[0];
}

__global__ __launch_bounds__(1024) void scan2_k(const int* bsum, int* boff, int nb) {
    __shared__ int sm[1024];
    int t = threadIdx.x;
    int v = (t < nb) ? bsum[t] : 0;
    sm[t] = v;
    __syncthreads();
    for (int off = 1; off < 1024; off <<= 1) {
        int x = (t >= off) ? sm[t - off] : 0;
        __syncthreads();
        sm[t] += x;
        __syncthreads();
    }
    if (t < nb) boff[t] = sm[t] - v;   // exclusive
}

__global__ __launch_bounds__(256) void scan3_k(const int* cnt, const int* boff, int* rowstart, int N_) {
    __shared__ int sm[256];
    int t = threadIdx.x, i = blockIdx.x * 256 + t;
    int v = (i < N_) ? cnt[i] : 0;
    sm[t] = v;
    __syncthreads();
    for (int off = 1; off < 256; off <<= 1) {
        int x = (t >= off) ? sm[t - off] : 0;
        __syncthreads();
        sm[t] += x;
        __syncthreads();
    }
    if (i < N_)  rowstart[i]  = boff[blockIdx.x] + sm[t] - v;
    if (i == N_ - 1) rowstart[N_] = boff[blockIdx.x] + sm[t];
}

// atomic-free CSR fill: pos = rowstart[c] + pofs[part][c] + rank
// csr entry: src:17 | unorm15(w) << 17
__global__ __launch_bounds__(256) void fill_csr_k(const unsigned long long* epack, const int* pofs,
                                                  const int* rowstart, unsigned int* cs,
                                                  int E_, int N_) {
    int e = blockIdx.x * 256 + threadIdx.x;
    if (e >= E_) return;
    unsigned long long v = __builtin_nontemporal_load(&epack[e]);
    unsigned int r   = (unsigned int)(v & 0x1ffffu);
    int          c   = (int)((v >> 17) & 0x1ffffu);
    unsigned int w15 = (unsigned int)((v >> 34) & 0x7fffu);
    int         part = (int)((v >> 49) & 7u);
    int           rk = (int)(v >> 52);
    int pos = rowstart[c] + pofs[(size_t)part * N_ + c] + rk;
    cs[pos] = r | (w15 << 17);
}

// 32-lane group per node: deg = 1 + sum(w over row, pads are 0); dinv = rsqrt
__global__ __launch_bounds__(256) void deg_dinv_k(const unsigned int* __restrict__ cs,
                                                  const int* __restrict__ rowstart,
                                                  float* __restrict__ dinv, int N_) {
    int node = blockIdx.x * 8 + (threadIdx.x >> 5);
    int l = threadIdx.x & 31;
    if (node >= N_) return;
    int s = rowstart[node], e = rowstart[node + 1];
    float sum = 0.0f;
    for (int j = s + l; j < e; j += 32) sum += (float)(cs[j] >> 17) * U15INV;
    #pragma unroll
    for (int off = 16; off; off >>= 1) sum += __shfl_xor(sum, off, 64);
    float d = sum + 1.0f;   // self-loop
    if (l == 0) dinv[node] = (d > 0.0f) ? rsqrtf(fmaxf(d, 1e-12f)) : 0.0f;
}

// 32-lane group per node: rewrite w -> unorm15(dinv[src]*w*dinv[dst]) in place
__global__ __launch_bounds__(256) void norm_k(unsigned int* __restrict__ cs,
                                              const int* __restrict__ rowstart,
                                              const float* __restrict__ dinv, int N_) {
    int node = blockIdx.x * 8 + (threadIdx.x >> 5);
    int l = threadIdx.x & 31;
    if (node >= N_) return;
    int s = rowstart[node], e = rowstart[node + 1];
    float dc = dinv[node];
    for (int j = s + l; j < e; j += 32) {
        unsigned int v = cs[j];
        unsigned int src = v & 0x1ffffu;
        float w = (float)(v >> 17) * U15INV;
        float nm = dinv[src] * w * dc;
        cs[j] = src | (u15q(nm) << 17);
    }
}

// fused weight prep:
// idx < F*D:  W1bT[n][k] = bf16( W1[k][n] * sigmoid_mask(xw[k]) )
// else:       W2bT[n][k] = bf16( W2[k][n] )
__global__ __launch_bounds__(256) void wprep_k(const float* W1, const float* xw, unsigned short* W1bT,
                                               const float* W2, unsigned short* W2bT,
                                               int F_, int D_, int C_) {
    int i = blockIdx.x * 256 + threadIdx.x;
    int n1 = F_ * D_;
    if (i < n1) {
        int k = i / D_, n = i % D_;
        float t = xw[k];
        float s = (fabsf(t) > 0.0f) ? 1.0f / (1.0f + expf(-t)) : 0.0f;
        W1bT[(size_t)n * F_ + k] = f2bf(W1[i] * s);
    } else if (i < n1 + D_ * C_) {
        int j = i - n1;
        int k = j / C_, n = j % C_;
        W2bT[(size_t)n * D_ + k] = f2bf(W2[j]);
    }
}

// ---------------- gemm1: 512 threads, tile 128 x 256 (full D in one block) ----------------
__global__ __launch_bounds__(512) void gemm1_512_k(const float* __restrict__ A,
                                                   const unsigned short* __restrict__ BT,
                                                   const float* __restrict__ bias,
                                                   unsigned short* __restrict__ C,
                                                   int M, int K, int Nn) {
    const int BK = 32;
    __shared__ __align__(16) unsigned short Asl[2][4][128][8];   // 16KB
    __shared__ __align__(16) unsigned short Bsl[2][4][256][8];   // 32KB

    int tid = threadIdx.x;
    int row0 = blockIdx.x * 128;
    int wid = tid >> 6, lane = tid & 63;
    int wm = wid & 1, wn = wid >> 1;           // 2x4 wave grid, wave tile 64x64
    int lrow = lane & 15, kg = lane >> 4;

    f32x4 acc[4][4];
    #pragma unroll
    for (int i = 0; i < 4; ++i)
        #pragma unroll
        for (int j = 0; j < 4; ++j) acc[i][j] = (f32x4){0.f, 0.f, 0.f, 0.f};

    int ar = tid >> 2, akg = tid & 3;          // A: row, kgroup (8 floats)
    int agrow = row0 + ar;
    bool avalid = agrow < M;
    int bn_ = tid >> 1, bkh = (tid & 1) * 16;  // B: col, k-half (16 bf16)

    float fa[8];
    bf16x8 bv0, bv1;

    auto loadTile = [&](int k0) {
        if (avalid) {
            const f32x4* p = (const f32x4*)&A[(size_t)agrow * K + k0 + akg * 8];
            *(f32x4*)&fa[0] = p[0];
            *(f32x4*)&fa[4] = p[1];
        }
        const bf16x8* p = (const bf16x8*)&BT[(size_t)bn_ * K + k0 + bkh];
        bv0 = p[0]; bv1 = p[1];
    };
    auto stageTile = [&](int buf) {
        unsigned short av[8];
        #pragma unroll
        for (int q = 0; q < 8; ++q) av[q] = avalid ? f2bf(fa[q]) : (unsigned short)0;
        *(bf16x8*)&Asl[buf][akg][ar][0] = *(bf16x8*)&av[0];
        *(bf16x8*)&Bsl[buf][(bkh >> 3) + 0][bn_][0] = bv0;
        *(bf16x8*)&Bsl[buf][(bkh >> 3) + 1][bn_][0] = bv1;
    };

    int nsteps = K / BK;
    loadTile(0);
    stageTile(0);
    __syncthreads();

    int cur = 0;
    for (int step = 0; step < nsteps; ++step) {
        bool more = (step + 1) < nsteps;
        if (more) loadTile((step + 1) * BK);

        bf16x8 af[4], bfr[4];
        #pragma unroll
        for (int i = 0; i < 4; ++i)
            af[i] = *(bf16x8*)&Asl[cur][kg][wm * 64 + i * 16 + lrow][0];
        #pragma unroll
        for (int j = 0; j < 4; ++j)
            bfr[j] = *(bf16x8*)&Bsl[cur][kg][wn * 64 + j * 16 + lrow][0];
        #pragma unroll
        for (int i = 0; i < 4; ++i)
            #pragma unroll
            for (int j = 0; j < 4; ++j)
                acc[i][j] = __builtin_amdgcn_mfma_f32_16x16x32_bf16(af[i], bfr[j], acc[i][j], 0, 0, 0);

        if (more) stageTile(cur ^ 1);
        __syncthreads();
        cur ^= 1;
    }

    #pragma unroll
    for (int i = 0; i < 4; ++i) {
        #pragma unroll
        for (int j = 0; j < 4; ++j) {
            int col = wn * 64 + j * 16 + lrow;
            float bv = bias[col];
            #pragma unroll
            for (int r = 0; r < 4; ++r) {
                int grow = row0 + wm * 64 + i * 16 + kg * 4 + r;
                if (grow < M) {
                    float v = fmaxf(acc[i][j][r] + bv, 0.0f);
                    C[(size_t)grow * Nn + col] = f2bf(v);
                }
            }
        }
    }
}

// ---------------- gemm2 (256 threads, BN=64, A bf16) ----------------
__global__ __launch_bounds__(256) void gemm2_k(const unsigned short* __restrict__ Ab,
                                               const unsigned short* __restrict__ BT,
                                               const float* __restrict__ bias,
                                               unsigned short* __restrict__ C,
                                               int M, int K, int Nn) {
    const int BN = 64, BK = 32;
    __shared__ __align__(16) unsigned short Asl[2][4][128][8];
    __shared__ __align__(16) unsigned short Bsl[2][4][BN][8];

    int tid = threadIdx.x;
    int row0 = blockIdx.x * 128;
    int wid = tid >> 6, lane = tid & 63;
    int wm = wid & 1, wn = wid >> 1;           // 2x2, wave 64 x 32
    const int NT = BN / 32;
    int lrow = lane & 15, kg = lane >> 4;

    f32x4 acc[4][NT];
    #pragma unroll
    for (int i = 0; i < 4; ++i)
        #pragma unroll
        for (int j = 0; j < NT; ++j) acc[i][j] = (f32x4){0.f, 0.f, 0.f, 0.f};

    int ar = tid >> 1, akh = (tid & 1) * 16;
    int agrow = row0 + ar;
    bool avalid = agrow < M;
    int bn_ = tid >> 1, bkh = (tid & 1) * 16;
    bool bvalid = bn_ < BN;

    unsigned short ha[16];
    bf16x8 bv0, bv1;

    auto loadTile = [&](int k0) {
        if (avalid) {
            const bf16x8* p = (const bf16x8*)&Ab[(size_t)agrow * K + k0 + akh];
            *(bf16x8*)&ha[0] = p[0];
            *(bf16x8*)&ha[8] = p[1];
        }
        if (bvalid) {
            const bf16x8* p = (const bf16x8*)&BT[(size_t)bn_ * K + k0 + bkh];
            bv0 = p[0]; bv1 = p[1];
        }
    };
    auto stageTile = [&](int buf) {
        unsigned short av[16];
        #pragma unroll
        for (int q = 0; q < 16; ++q) av[q] = avalid ? ha[q] : (unsigned short)0;
        *(bf16x8*)&Asl[buf][(akh >> 3) + 0][ar][0] = *(bf16x8*)&av[0];
        *(bf16x8*)&Asl[buf][(akh >> 3) + 1][ar][0] = *(bf16x8*)&av[8];
        if (bvalid) {
            *(bf16x8*)&Bsl[buf][(bkh >> 3) + 0][bn_][0] = bv0;
            *(bf16x8*)&Bsl[buf][(bkh >> 3) + 1][bn_][0] = bv1;
        }
    };

    int nsteps = K / BK;
    loadTile(0);
    stageTile(0);
    __syncthreads();

    int cur = 0;
    for (int step = 0; step < nsteps; ++step) {
        bool more = (step + 1) < nsteps;
        if (more) loadTile((step + 1) * BK);

        bf16x8 af[4], bfr[NT];
        #pragma unroll
        for (int i = 0; i < 4; ++i)
            af[i] = *(bf16x8*)&Asl[cur][kg][wm * 64 + i * 16 + lrow][0];
        #pragma unroll
        for (int j = 0; j < NT; ++j)
            bfr[j] = *(bf16x8*)&Bsl[cur][kg][wn * (BN / 2) + j * 16 + lrow][0];
        #pragma unroll
        for (int i = 0; i < 4; ++i)
            #pragma unroll
            for (int j = 0; j < NT; ++j)
                acc[i][j] = __builtin_amdgcn_mfma_f32_16x16x32_bf16(af[i], bfr[j], acc[i][j], 0, 0, 0);

        if (more) stageTile(cur ^ 1);
        __syncthreads();
        cur ^= 1;
    }

    #pragma unroll
    for (int i = 0; i < 4; ++i) {
        #pragma unroll
        for (int j = 0; j < NT; ++j) {
            int col = wn * (BN / 2) + j * 16 + lrow;
            float bv = bias[col];
            #pragma unroll
            for (int r = 0; r < 4; ++r) {
                int grow = row0 + wm * 64 + i * 16 + kg * 4 + r;
                if (grow < M)
                    C[(size_t)grow * Nn + col] = f2bf(acc[i][j][r] + bv);
            }
        }
    }
}

// ---------------- propagation: 8 lanes per node, 8 nodes per wave ----------------
template<bool LAST>
__global__ __launch_bounds__(256) void prop8_k(const unsigned short* __restrict__ z,
                                               const unsigned short* __restrict__ z0,
                                               const int* __restrict__ rowstart,
                                               const unsigned int* __restrict__ cs,
                                               const float* __restrict__ dinv,
                                               unsigned short* __restrict__ znew,
                                               float* __restrict__ out, int N_) {
    int node = blockIdx.x * 32 + (threadIdx.x >> 3);
    int l = threadIdx.x & 7;
    if (node >= N_) return;
    int s = rowstart[node], e = rowstart[node + 1];   // multiples of 8
    float d = dinv[node];
    size_t ro = (size_t)node * 64 + l * 8;
    u32x4 zs = *(const u32x4*)&z[ro];
    float dd = d * d;
    float a[8];
    a[0] = dd * bflo(zs.x); a[1] = dd * bfhi(zs.x);
    a[2] = dd * bflo(zs.y); a[3] = dd * bfhi(zs.y);
    a[4] = dd * bflo(zs.z); a[5] = dd * bfhi(zs.z);
    a[6] = dd * bflo(zs.w); a[7] = dd * bfhi(zs.w);

    for (int j = s; j < e; j += 8) {
        u32x4 p0 = __builtin_nontemporal_load((const u32x4*)&cs[j]);
        u32x4 p1 = __builtin_nontemporal_load((const u32x4*)&cs[j + 4]);
        unsigned int pe[8] = { p0.x, p0.y, p0.z, p0.w, p1.x, p1.y, p1.z, p1.w };
        u32x4 g[8];
        #pragma unroll
        for (int q = 0; q < 8; ++q)
            g[q] = *(const u32x4*)&z[(size_t)(pe[q] & 0x1ffffu) * 64 + l * 8];
        #pragma unroll
        for (int q = 0; q < 8; ++q) {
            float w = (float)(pe[q] >> 17) * U15INV;
            a[0] += w * bflo(g[q].x); a[1] += w * bfhi(g[q].x);
            a[2] += w * bflo(g[q].y); a[3] += w * bfhi(g[q].y);
            a[4] += w * bflo(g[q].z); a[5] += w * bfhi(g[q].z);
            a[6] += w * bflo(g[q].w); a[7] += w * bfhi(g[q].w);
        }
    }

    u32x4 z0v = __builtin_nontemporal_load((const u32x4*)&z0[ro]);
    float v[8];
    float z0f[8] = { bflo(z0v.x), bfhi(z0v.x), bflo(z0v.y), bfhi(z0v.y),
                     bflo(z0v.z), bfhi(z0v.z), bflo(z0v.w), bfhi(z0v.w) };
    #pragma unroll
    for (int q = 0; q < 8; ++q) v[q] = (1.0f - ALPHA) * a[q] + ALPHA * z0f[q];

    if (!LAST) {
        u32x4 o;
        o.x = pack2(v[0], v[1]); o.y = pack2(v[2], v[3]);
        o.z = pack2(v[4], v[5]); o.w = pack2(v[6], v[7]);
        *(u32x4*)&znew[ro] = o;      // normal store: let z dwell in L2
    } else {
        float m = v[0];
        #pragma unroll
        for (int q = 1; q < 8; ++q) m = fmaxf(m, v[q]);
        #pragma unroll
        for (int off = 1; off < 8; off <<= 1) m = fmaxf(m, __shfl_xor(m, off, 64));
        float sum = 0.0f;
        #pragma unroll
        for (int q = 0; q < 8; ++q) sum += expf(v[q] - m);
        #pragma unroll
        for (int off = 1; off < 8; off <<= 1) sum += __shfl_xor(sum, off, 64);
        float lg = logf(sum);
        float4 o0 = make_float4(v[0] - m - lg, v[1] - m - lg, v[2] - m - lg, v[3] - m - lg);
        float4 o1 = make_float4(v[4] - m - lg, v[5] - m - lg, v[6] - m - lg, v[7] - m - lg);
        *(float4*)&out[ro] = o0;
        *(float4*)&out[ro + 4] = o1;
    }
}

// ---------------- launcher ----------------

extern "C" void kernel_launch(void* const* d_in, const int* in_sizes, int n_in,
                              void* d_out, int out_size, void* d_ws, size_t ws_size,
                              hipStream_t stream) {
    const float* x   = (const float*)d_in[0];
    const void*  ei  = d_in[1];
    const float* ew  = (const float*)d_in[2];
    const float* xw  = (const float*)d_in[3];
    const float* W1  = (const float*)d_in[4];
    const float* b1  = (const float*)d_in[5];
    const float* W2  = (const float*)d_in[6];
    const float* b2  = (const float*)d_in[7];

    const int F_ = in_sizes[3];          // 512
    const int N_ = in_sizes[0] / F_;     // 100000
    const int E_ = in_sizes[2];          // 3200000
    const int D_ = in_sizes[5];          // 256
    const int C_ = in_sizes[7];          // 64

    const int E8 = E_ + 7 * N_;          // upper bound on padded edge count

    char* base = (char*)d_ws;
    size_t off = 0;
    auto take = [&](size_t bytes) -> void* {
        void* p = base + off;
        off += (bytes + 255) & ~(size_t)255;
        return p;
    };
    unsigned long long* epack = (unsigned long long*)take((size_t)E_ * 8);
    unsigned int* cs = (unsigned int*)take((size_t)E8 * 4);
    int*   cntp     = (int*)  take((size_t)NPART * N_ * 4);
    int*   pofs     = (int*)  take((size_t)NPART * N_ * 4);
    int*   cnt8     = (int*)  take((size_t)N_ * 4);
    float* dinv     = (float*)take((size_t)N_ * 4);
    int*   rowstart = (int*)  take((size_t)(N_ + 1) * 4);
    int*   flag     = (int*)  take(256);
    int*   bsum     = (int*)  take(4096 * 4);
    int*   boff     = (int*)  take(4096 * 4);
    unsigned short* W1bT = (unsigned short*)take((size_t)F_ * D_ * 2);
    unsigned short* W2bT = (unsigned short*)take((size_t)D_ * C_ * 2);
    unsigned short* h    = (unsigned short*)take((size_t)N_ * D_ * 2);
    unsigned short* z0b  = (unsigned short*)take((size_t)N_ * C_ * 2);
    unsigned short* za   = (unsigned short*)take((size_t)N_ * C_ * 2);
    unsigned short* zb   = (unsigned short*)take((size_t)N_ * C_ * 2);

    (void)ws_size; (void)n_in; (void)out_size;

    int nblk = (N_ + 255) / 256;
    int eblk = (E_ + 255) / 256;
    int ncnt = NPART * N_;
    int setup_blk = ((ncnt > E8 ? ncnt : E8) + 255) / 256;

    setup_k<<<setup_blk, 256, 0, stream>>>(cntp, cs, flag, ncnt, E8);
    detect_idx_k<<<1, 256, 0, stream>>>(ei, flag, E_, N_);
    prep_edges_k<<<eblk, 256, 0, stream>>>(ei, ew, epack, cntp, flag, E_, N_);
    combine_k<<<nblk, 256, 0, stream>>>(cntp, pofs, cnt8, N_);
    scan1_k<<<nblk, 256, 0, stream>>>(cnt8, bsum, N_);
    scan2_k<<<1, 1024, 0, stream>>>(bsum, boff, nblk);
    scan3_k<<<nblk, 256, 0, stream>>>(cnt8, boff, rowstart, N_);
    fill_csr_k<<<eblk, 256, 0, stream>>>(epack, pofs, rowstart, cs, E_, N_);
    int gblk8 = (N_ + 7) / 8;
    deg_dinv_k<<<gblk8, 256, 0, stream>>>(cs, rowstart, dinv, N_);
    norm_k<<<gblk8, 256, 0, stream>>>(cs, rowstart, dinv, N_);
    wprep_k<<<(F_ * D_ + D_ * C_ + 255) / 256, 256, 0, stream>>>(W1, xw, W1bT, W2, W2bT, F_, D_, C_);

    int gx = (N_ + 127) / 128;
    // gemm1: h = relu(x @ W1p + b1); 512-thread blocks, full D per block -> x read once
    gemm1_512_k<<<gx, 512, 0, stream>>>(x, W1bT, b1, h, N_, F_, D_);
    // gemm2: z0 = h @ W2 + b2
    gemm2_k<<<gx, 256, 0, stream>>>(h, W2bT, b2, z0b, N_, D_, C_);

    int pblk = (N_ + 31) / 32;
    const unsigned short* cur = z0b;
    unsigned short* bufs[2] = { za, zb };
    for (int it = 0; it < K_ITERS - 1; ++it) {
        unsigned short* dst = bufs[it & 1];
        prop8_k<false><<<pblk, 256, 0, stream>>>(cur, z0b, rowstart, cs, dinv, dst, nullptr, N_);
        cur = dst;
    }
    prop8_k<true><<<pblk, 256, 0, stream>>>(cur, z0b, rowstart, cs, dinv, nullptr, (float*)d_out, N_);
}

// Round 15
// 874.997 us; speedup vs baseline: 1.0661x; 1.0661x over previous
//
#include <hip/hip_runtime.h>
#include <hip/hip_bf16.h>
#include <cstdint>
#include <cstddef>

#define ALPHA 0.1f
#define K_ITERS 10
#define NPART 8

typedef __attribute__((ext_vector_type(8))) short bf16x8;
typedef __attribute__((ext_vector_type(4))) float f32x4;
typedef __attribute__((ext_vector_type(4))) unsigned int u32x4;

#define U15INV (1.0f / 32767.0f)

__device__ __forceinline__ unsigned short f2bf(float f) {
    unsigned int u = __float_as_uint(f);
    u += 0x7fffu + ((u >> 16) & 1u);          // RNE
    return (unsigned short)(u >> 16);
}
__device__ __forceinline__ float bflo(unsigned int u) {
    return __uint_as_float(u << 16);
}
__device__ __forceinline__ float bfhi(unsigned int u) {
    return __uint_as_float(u & 0xffff0000u);
}
__device__ __forceinline__ unsigned int pack2(float a, float b) {
    return (unsigned int)f2bf(a) | ((unsigned int)f2bf(b) << 16);
}
__device__ __forceinline__ unsigned int u15q(float w) {   // w in [0,1]
    return (unsigned int)(w * 32767.0f + 0.5f);
}
__device__ __forceinline__ int xcd_id() {
    unsigned int x;
    asm volatile("s_getreg_b32 %0, hwreg(20, 0, 32)" : "=s"(x));   // HW_REG_XCC_ID (gfx950)
    return (int)(x & (NPART - 1));
}

// ---------------- helper kernels ----------------

// combined setup: zero cnt partitions, flag, and csr buffer
__global__ __launch_bounds__(256) void setup_k(int* cntp, unsigned int* cs, int* flag,
                                               int ncnt, int ncs) {
    int i = blockIdx.x * 256 + threadIdx.x;
    if (i == 0) *flag = 0;
    if (i < ncnt) cntp[i] = 0;
    if (i < ncs) cs[i] = 0;    // src=0, w=0 -> contributes 0
}

// Detect whether edge_index buffer is int64 (values in [0,N) when read as ll) or int32.
__global__ void detect_idx_k(const void* ei, int* flag, int E_, int N_) {
    int tid = threadIdx.x;
    const long long* p = (const long long*)ei;
    int bad = 0;
    int lim = (E_ < 4096) ? E_ : 4096;
    for (int i = tid; i < lim; i += 256) {
        long long v = p[i];
        if (v < 0 || v >= (long long)N_) bad = 1;
    }
    if (bad) atomicOr(flag, 1);   // 1 => buffer is int32
}

// decode indices, sigmoid-masked w (unorm15), XCD-local histogram rank.
// Workgroup-scope atomic executes in the LOCAL XCD L2 (partition slab touched
// only by that XCD -> atomicity holds; kernel boundary flushes before combine).
// epack u64: r:17 | c:17<<17 | w15<<34 | part:3<<49 | rank:12<<52
__global__ __launch_bounds__(256) void prep_edges_k(const void* ei, const float* ew,
                                                    unsigned long long* epack, int* cntp,
                                                    const int* flag, int E_, int N_) {
    int e = blockIdx.x * 256 + threadIdx.x;
    if (e >= E_) return;
    int is32 = *flag;
    unsigned long long r, c;
    if (is32) {
        const int* p = (const int*)ei;
        r = (unsigned long long)(unsigned int)p[e];
        c = (unsigned long long)(unsigned int)p[(size_t)E_ + e];
    } else {
        const long long* p = (const long long*)ei;
        r = (unsigned long long)p[e];
        c = (unsigned long long)p[(size_t)E_ + e];
    }
    float t = ew[e];
    float wv = (fabsf(t) > 0.0f) ? 1.0f / (1.0f + expf(-t)) : 0.0f;
    unsigned long long part = (unsigned long long)xcd_id();
    unsigned long long rk = (unsigned long long)(unsigned int)
        __hip_atomic_fetch_add(&cntp[(size_t)part * N_ + (int)c], 1,
                               __ATOMIC_RELAXED, __HIP_MEMORY_SCOPE_WORKGROUP);
    epack[e] = r | (c << 17) | ((unsigned long long)u15q(wv) << 34)
                 | (part << 49) | (rk << 52);
}

// per-node: prefix over NPART partition counts -> pofs; padded total -> cnt8
__global__ __launch_bounds__(256) void combine_k(const int* cntp, int* pofs, int* cnt8, int N_) {
    int i = blockIdx.x * 256 + threadIdx.x;
    if (i >= N_) return;
    int s = 0;
    #pragma unroll
    for (int p = 0; p < NPART; ++p) {
        size_t idx = (size_t)p * N_ + i;
        int v = cntp[idx];
        pofs[idx] = s;
        s += v;
    }
    cnt8[i] = (s + 7) & ~7;   // pad rows to multiple of 8
}

// hierarchical exclusive scan of cnt8 -> rowstart
__global__ __launch_bounds__(256) void scan1_k(const int* cnt, int* bsum, int N_) {
    __shared__ int sm[256];
    int t = threadIdx.x, i = blockIdx.x * 256 + t;
    sm[t] = (i < N_) ? cnt[i] : 0;
    __syncthreads();
    for (int off = 128; off; off >>= 1) {
        if (t < off) sm[t] += sm[t + off];
        __syncthreads();
    }
    if (t == 0) bsum[blockIdx.x] = sm[0];
}

__global__ __launch_bounds__(1024) void scan2_k(const int* bsum, int* boff, int nb) {
    __shared__ int sm[1024];
    int t = threadIdx.x;
    int v = (t < nb) ? bsum[t] : 0;
    sm[t] = v;
    __syncthreads();
    for (int off = 1; off < 1024; off <<= 1) {
        int x = (t >= off) ? sm[t - off] : 0;
        __syncthreads();
        sm[t] += x;
        __syncthreads();
    }
    if (t < nb) boff[t] = sm[t] - v;   // exclusive
}

__global__ __launch_bounds__(256) void scan3_k(const int* cnt, const int* boff, int* rowstart, int N_) {
    __shared__ int sm[256];
    int t = threadIdx.x, i = blockIdx.x * 256 + t;
    int v = (i < N_) ? cnt[i] : 0;
    sm[t] = v;
    __syncthreads();
    for (int off = 1; off < 256; off <<= 1) {
        int x = (t >= off) ? sm[t - off] : 0;
        __syncthreads();
        sm[t] += x;
        __syncthreads();
    }
    if (i < N_)  rowstart[i]  = boff[blockIdx.x] + sm[t] - v;
    if (i == N_ - 1) rowstart[N_] = boff[blockIdx.x] + sm[t];
}

// atomic-free CSR fill: pos = rowstart[c] + pofs[part][c] + rank
// csr entry: src:17 | unorm15(w) << 17
__global__ __launch_bounds__(256) void fill_csr_k(const unsigned long long* epack, const int* pofs,
                                                  const int* rowstart, unsigned int* cs,
                                                  int E_, int N_) {
    int e = blockIdx.x * 256 + threadIdx.x;
    if (e >= E_) return;
    unsigned long long v = epack[e];
    unsigned int r   = (unsigned int)(v & 0x1ffffu);
    int          c   = (int)((v >> 17) & 0x1ffffu);
    unsigned int w15 = (unsigned int)((v >> 34) & 0x7fffu);
    int         part = (int)((v >> 49) & 7u);
    int           rk = (int)(v >> 52);
    int pos = rowstart[c] + pofs[(size_t)part * N_ + c] + rk;
    cs[pos] = r | (w15 << 17);
}

// 32-lane group per node: deg = 1 + sum(w over row, pads are 0); dinv = rsqrt
__global__ __launch_bounds__(256) void deg_dinv_k(const unsigned int* __restrict__ cs,
                                                  const int* __restrict__ rowstart,
                                                  float* __restrict__ dinv, int N_) {
    int node = blockIdx.x * 8 + (threadIdx.x >> 5);
    int l = threadIdx.x & 31;
    if (node >= N_) return;
    int s = rowstart[node], e = rowstart[node + 1];
    float sum = 0.0f;
    for (int j = s + l; j < e; j += 32) sum += (float)(cs[j] >> 17) * U15INV;
    #pragma unroll
    for (int off = 16; off; off >>= 1) sum += __shfl_xor(sum, off, 64);
    float d = sum + 1.0f;   // self-loop
    if (l == 0) dinv[node] = (d > 0.0f) ? rsqrtf(fmaxf(d, 1e-12f)) : 0.0f;
}

// 32-lane group per node: rewrite w -> unorm15(dinv[src]*w*dinv[dst]) in place
__global__ __launch_bounds__(256) void norm_k(unsigned int* __restrict__ cs,
                                              const int* __restrict__ rowstart,
                                              const float* __restrict__ dinv, int N_) {
    int node = blockIdx.x * 8 + (threadIdx.x >> 5);
    int l = threadIdx.x & 31;
    if (node >= N_) return;
    int s = rowstart[node], e = rowstart[node + 1];
    float dc = dinv[node];
    for (int j = s + l; j < e; j += 32) {
        unsigned int v = cs[j];
        unsigned int src = v & 0x1ffffu;
        float w = (float)(v >> 17) * U15INV;
        float nm = dinv[src] * w * dc;
        cs[j] = src | (u15q(nm) << 17);
    }
}

// fused weight prep:
// idx < F*D:  W1bT[n][k] = bf16( W1[k][n] * sigmoid_mask(xw[k]) )
// else:       W2bT[n][k] = bf16( W2[k][n] )
__global__ __launch_bounds__(256) void wprep_k(const float* W1, const float* xw, unsigned short* W1bT,
                                               const float* W2, unsigned short* W2bT,
                                               int F_, int D_, int C_) {
    int i = blockIdx.x * 256 + threadIdx.x;
    int n1 = F_ * D_;
    if (i < n1) {
        int k = i / D_, n = i % D_;
        float t = xw[k];
        float s = (fabsf(t) > 0.0f) ? 1.0f / (1.0f + expf(-t)) : 0.0f;
        W1bT[(size_t)n * F_ + k] = f2bf(W1[i] * s);
    } else if (i < n1 + D_ * C_) {
        int j = i - n1;
        int k = j / C_, n = j % C_;
        W2bT[(size_t)n * D_ + k] = f2bf(W2[j]);
    }
}

// ---------------- FUSED MLP: z0 = (relu(x @ W1p + b1)) @ W2 + b2 ----------------
// 512 threads, 8 waves (2x4), block tile 128 rows x full D=256.
// Phase 1: main K-loop over F with double-buffered LDS staging.
// Phase 2: bias+relu h tile -> 64KB LDS (bf16, A-fragment layout).
// Phase 3: per-wave 64x16 slice of z0 over K2=D; W2bT B-frags read from global
//          (32KB, L2-resident). h never touches global memory.
__global__ __launch_bounds__(512) void gemm_fused_k(const float* __restrict__ A,
                                                    const unsigned short* __restrict__ BT,
                                                    const float* __restrict__ b1,
                                                    const unsigned short* __restrict__ W2bT,
                                                    const float* __restrict__ b2,
                                                    unsigned short* __restrict__ z0out,
                                                    int M, int K, int Nn, int Cn) {
    const int BK = 32;
    __shared__ __align__(16) unsigned short SMEM[32768];   // 64KB union
    // phase-1 views: Asl [2][4][128][8] @0, Bsl [2][4][256][8] @8192
    typedef unsigned short (*AslT)[4][128][8];
    typedef unsigned short (*BslT)[4][256][8];
    AslT Asl = (AslT)SMEM;
    BslT Bsl = (BslT)(SMEM + 8192);
    // phase-2/3 view: Hsl[chunk(8)][kgroup(4)][row(128)][8] == SMEM flat

    int tid = threadIdx.x;
    int row0 = blockIdx.x * 128;
    int wid = tid >> 6, lane = tid & 63;
    int wm = wid & 1, wn = wid >> 1;           // 2x4 wave grid, wave tile 64x64
    int lrow = lane & 15, kg = lane >> 4;

    f32x4 acc[4][4];
    #pragma unroll
    for (int i = 0; i < 4; ++i)
        #pragma unroll
        for (int j = 0; j < 4; ++j) acc[i][j] = (f32x4){0.f, 0.f, 0.f, 0.f};

    int ar = tid >> 2, akg = tid & 3;          // A: row, kgroup (8 floats)
    int agrow = row0 + ar;
    bool avalid = agrow < M;
    int bn_ = tid >> 1, bkh = (tid & 1) * 16;  // B: col, k-half (16 bf16)

    float fa[8];
    bf16x8 bv0, bv1;

    auto loadTile = [&](int k0) {
        if (avalid) {
            const f32x4* p = (const f32x4*)&A[(size_t)agrow * K + k0 + akg * 8];
            *(f32x4*)&fa[0] = p[0];
            *(f32x4*)&fa[4] = p[1];
        }
        const bf16x8* p = (const bf16x8*)&BT[(size_t)bn_ * K + k0 + bkh];
        bv0 = p[0]; bv1 = p[1];
    };
    auto stageTile = [&](int buf) {
        unsigned short av[8];
        #pragma unroll
        for (int q = 0; q < 8; ++q) av[q] = avalid ? f2bf(fa[q]) : (unsigned short)0;
        *(bf16x8*)&Asl[buf][akg][ar][0] = *(bf16x8*)&av[0];
        *(bf16x8*)&Bsl[buf][(bkh >> 3) + 0][bn_][0] = bv0;
        *(bf16x8*)&Bsl[buf][(bkh >> 3) + 1][bn_][0] = bv1;
    };

    int nsteps = K / BK;
    loadTile(0);
    stageTile(0);
    __syncthreads();

    int cur = 0;
    for (int step = 0; step < nsteps; ++step) {
        bool more = (step + 1) < nsteps;
        if (more) loadTile((step + 1) * BK);

        bf16x8 af[4], bfr[4];
        #pragma unroll
        for (int i = 0; i < 4; ++i)
            af[i] = *(bf16x8*)&Asl[cur][kg][wm * 64 + i * 16 + lrow][0];
        #pragma unroll
        for (int j = 0; j < 4; ++j)
            bfr[j] = *(bf16x8*)&Bsl[cur][kg][wn * 64 + j * 16 + lrow][0];
        #pragma unroll
        for (int i = 0; i < 4; ++i)
            #pragma unroll
            for (int j = 0; j < 4; ++j)
                acc[i][j] = __builtin_amdgcn_mfma_f32_16x16x32_bf16(af[i], bfr[j], acc[i][j], 0, 0, 0);

        if (more) stageTile(cur ^ 1);
        __syncthreads();
        cur ^= 1;
    }
    // after final barrier all staging reads done -> safe to overwrite SMEM

    // ---- phase 2: h tile (bias+relu, bf16) into Hsl ----
    // acc[i][j][r]: row = wm*64+i*16+kg*4+r, hcol(k2) = wn*64+j*16+lrow
    // Hsl addr for (row, k2): ((k2>>5)*4 + ((k2>>3)&3))*1024 + row*8 + (k2&7)
    #pragma unroll
    for (int i = 0; i < 4; ++i) {
        #pragma unroll
        for (int j = 0; j < 4; ++j) {
            int k2 = wn * 64 + j * 16 + lrow;
            float bv = b1[k2];
            int base = ((k2 >> 5) * 4 + ((k2 >> 3) & 3)) * 1024 + (k2 & 7);
            #pragma unroll
            for (int r = 0; r < 4; ++r) {
                int row = wm * 64 + i * 16 + kg * 4 + r;
                float v = fmaxf(acc[i][j][r] + bv, 0.0f);
                SMEM[base + row * 8] = f2bf(v);
            }
        }
    }
    __syncthreads();

    // ---- phase 3: z0 slice: wave (wm, wn) -> rows wm*64.., cols wn*16+lrow ----
    f32x4 acc2[4];
    #pragma unroll
    for (int i = 0; i < 4; ++i) acc2[i] = (f32x4){0.f, 0.f, 0.f, 0.f};
    int col2 = wn * 16 + lrow;
    #pragma unroll
    for (int ch = 0; ch < 8; ++ch) {           // K2 = Nn = 256 -> 8 chunks of 32
        bf16x8 bfr2 = *(const bf16x8*)&W2bT[(size_t)col2 * Nn + ch * 32 + kg * 8];
        bf16x8 af2[4];
        #pragma unroll
        for (int i = 0; i < 4; ++i)
            af2[i] = *(bf16x8*)&SMEM[(ch * 4 + kg) * 1024 + (wm * 64 + i * 16 + lrow) * 8];
        #pragma unroll
        for (int i = 0; i < 4; ++i)
            acc2[i] = __builtin_amdgcn_mfma_f32_16x16x32_bf16(af2[i], bfr2, acc2[i], 0, 0, 0);
    }
    float bv2 = b2[col2];
    #pragma unroll
    for (int i = 0; i < 4; ++i) {
        #pragma unroll
        for (int r = 0; r < 4; ++r) {
            int grow = row0 + wm * 64 + i * 16 + kg * 4 + r;
            if (grow < M)
                z0out[(size_t)grow * Cn + col2] = f2bf(acc2[i][r] + bv2);
        }
    }
}

// ---------------- propagation: 8 lanes per node, 8 nodes per wave ----------------
template<bool LAST>
__global__ __launch_bounds__(256) void prop8_k(const unsigned short* __restrict__ z,
                                               const unsigned short* __restrict__ z0,
                                               const int* __restrict__ rowstart,
                                               const unsigned int* __restrict__ cs,
                                               const float* __restrict__ dinv,
                                               unsigned short* __restrict__ znew,
                                               float* __restrict__ out, int N_) {
    int node = blockIdx.x * 32 + (threadIdx.x >> 3);
    int l = threadIdx.x & 7;
    if (node >= N_) return;
    int s = rowstart[node], e = rowstart[node + 1];   // multiples of 8
    float d = dinv[node];
    size_t ro = (size_t)node * 64 + l * 8;
    u32x4 zs = *(const u32x4*)&z[ro];
    float dd = d * d;
    float a[8];
    a[0] = dd * bflo(zs.x); a[1] = dd * bfhi(zs.x);
    a[2] = dd * bflo(zs.y); a[3] = dd * bfhi(zs.y);
    a[4] = dd * bflo(zs.z); a[5] = dd * bfhi(zs.z);
    a[6] = dd * bflo(zs.w); a[7] = dd * bfhi(zs.w);

    for (int j = s; j < e; j += 8) {
        u32x4 p0 = __builtin_nontemporal_load((const u32x4*)&cs[j]);
        u32x4 p1 = __builtin_nontemporal_load((const u32x4*)&cs[j + 4]);
        unsigned int pe[8] = { p0.x, p0.y, p0.z, p0.w, p1.x, p1.y, p1.z, p1.w };
        u32x4 g[8];
        #pragma unroll
        for (int q = 0; q < 8; ++q)
            g[q] = *(const u32x4*)&z[(size_t)(pe[q] & 0x1ffffu) * 64 + l * 8];
        #pragma unroll
        for (int q = 0; q < 8; ++q) {
            float w = (float)(pe[q] >> 17) * U15INV;
            a[0] += w * bflo(g[q].x); a[1] += w * bfhi(g[q].x);
            a[2] += w * bflo(g[q].y); a[3] += w * bfhi(g[q].y);
            a[4] += w * bflo(g[q].z); a[5] += w * bfhi(g[q].z);
            a[6] += w * bflo(g[q].w); a[7] += w * bfhi(g[q].w);
        }
    }

    u32x4 z0v = __builtin_nontemporal_load((const u32x4*)&z0[ro]);
    float v[8];
    float z0f[8] = { bflo(z0v.x), bfhi(z0v.x), bflo(z0v.y), bfhi(z0v.y),
                     bflo(z0v.z), bfhi(z0v.z), bflo(z0v.w), bfhi(z0v.w) };
    #pragma unroll
    for (int q = 0; q < 8; ++q) v[q] = (1.0f - ALPHA) * a[q] + ALPHA * z0f[q];

    if (!LAST) {
        u32x4 o;
        o.x = pack2(v[0], v[1]); o.y = pack2(v[2], v[3]);
        o.z = pack2(v[4], v[5]); o.w = pack2(v[6], v[7]);
        *(u32x4*)&znew[ro] = o;      // normal store: let z dwell in L2
    } else {
        float m = v[0];
        #pragma unroll
        for (int q = 1; q < 8; ++q) m = fmaxf(m, v[q]);
        #pragma unroll
        for (int off = 1; off < 8; off <<= 1) m = fmaxf(m, __shfl_xor(m, off, 64));
        float sum = 0.0f;
        #pragma unroll
        for (int q = 0; q < 8; ++q) sum += expf(v[q] - m);
        #pragma unroll
        for (int off = 1; off < 8; off <<= 1) sum += __shfl_xor(sum, off, 64);
        float lg = logf(sum);
        float4 o0 = make_float4(v[0] - m - lg, v[1] - m - lg, v[2] - m - lg, v[3] - m - lg);
        float4 o1 = make_float4(v[4] - m - lg, v[5] - m - lg, v[6] - m - lg, v[7] - m - lg);
        *(float4*)&out[ro] = o0;
        *(float4*)&out[ro + 4] = o1;
    }
}

// ---------------- launcher ----------------

extern "C" void kernel_launch(void* const* d_in, const int* in_sizes, int n_in,
                              void* d_out, int out_size, void* d_ws, size_t ws_size,
                              hipStream_t stream) {
    const float* x   = (const float*)d_in[0];
    const void*  ei  = d_in[1];
    const float* ew  = (const float*)d_in[2];
    const float* xw  = (const float*)d_in[3];
    const float* W1  = (const float*)d_in[4];
    const float* b1  = (const float*)d_in[5];
    const float* W2  = (const float*)d_in[6];
    const float* b2  = (const float*)d_in[7];

    const int F_ = in_sizes[3];          // 512
    const int N_ = in_sizes[0] / F_;     // 100000
    const int E_ = in_sizes[2];          // 3200000
    const int D_ = in_sizes[5];          // 256
    const int C_ = in_sizes[7];          // 64

    const int E8 = E_ + 7 * N_;          // upper bound on padded edge count

    char* base = (char*)d_ws;
    size_t off = 0;
    auto take = [&](size_t bytes) -> void* {
        void* p = base + off;
        off += (bytes + 255) & ~(size_t)255;
        return p;
    };
    unsigned long long* epack = (unsigned long long*)take((size_t)E_ * 8);
    unsigned int* cs = (unsigned int*)take((size_t)E8 * 4);
    int*   cntp     = (int*)  take((size_t)NPART * N_ * 4);
    int*   pofs     = (int*)  take((size_t)NPART * N_ * 4);
    int*   cnt8     = (int*)  take((size_t)N_ * 4);
    float* dinv     = (float*)take((size_t)N_ * 4);
    int*   rowstart = (int*)  take((size_t)(N_ + 1) * 4);
    int*   flag     = (int*)  take(256);
    int*   bsum     = (int*)  take(4096 * 4);
    int*   boff     = (int*)  take(4096 * 4);
    unsigned short* W1bT = (unsigned short*)take((size_t)F_ * D_ * 2);
    unsigned short* W2bT = (unsigned short*)take((size_t)D_ * C_ * 2);
    unsigned short* z0b  = (unsigned short*)take((size_t)N_ * C_ * 2);
    unsigned short* za   = (unsigned short*)take((size_t)N_ * C_ * 2);
    unsigned short* zb   = (unsigned short*)take((size_t)N_ * C_ * 2);

    (void)ws_size; (void)n_in; (void)out_size;

    int nblk = (N_ + 255) / 256;
    int eblk = (E_ + 255) / 256;
    int ncnt = NPART * N_;
    int setup_blk = ((ncnt > E8 ? ncnt : E8) + 255) / 256;

    setup_k<<<setup_blk, 256, 0, stream>>>(cntp, cs, flag, ncnt, E8);
    detect_idx_k<<<1, 256, 0, stream>>>(ei, flag, E_, N_);
    prep_edges_k<<<eblk, 256, 0, stream>>>(ei, ew, epack, cntp, flag, E_, N_);
    combine_k<<<nblk, 256, 0, stream>>>(cntp, pofs, cnt8, N_);
    scan1_k<<<nblk, 256, 0, stream>>>(cnt8, bsum, N_);
    scan2_k<<<1, 1024, 0, stream>>>(bsum, boff, nblk);
    scan3_k<<<nblk, 256, 0, stream>>>(cnt8, boff, rowstart, N_);
    fill_csr_k<<<eblk, 256, 0, stream>>>(epack, pofs, rowstart, cs, E_, N_);
    int gblk8 = (N_ + 7) / 8;
    deg_dinv_k<<<gblk8, 256, 0, stream>>>(cs, rowstart, dinv, N_);
    norm_k<<<gblk8, 256, 0, stream>>>(cs, rowstart, dinv, N_);
    wprep_k<<<(F_ * D_ + D_ * C_ + 255) / 256, 256, 0, stream>>>(W1, xw, W1bT, W2, W2bT, F_, D_, C_);

    int gx = (N_ + 127) / 128;
    // fused MLP: z0 = relu(x @ W1p + b1) @ W2 + b2 ; h never leaves the block
    gemm_fused_k<<<gx, 512, 0, stream>>>(x, W1bT, b1, W2bT, b2, z0b, N_, F_, D_, C_);

    int pblk = (N_ + 31) / 32;
    const unsigned short* cur = z0b;
    unsigned short* bufs[2] = { za, zb };
    for (int it = 0; it < K_ITERS - 1; ++it) {
        unsigned short* dst = bufs[it & 1];
        prop8_k<false><<<pblk, 256, 0, stream>>>(cur, z0b, rowstart, cs, dinv, dst, nullptr, N_);
        cur = dst;
    }
    prop8_k<true><<<pblk, 256, 0, stream>>>(cur, z0b, rowstart, cs, dinv, nullptr, (float*)d_out, N_);
}

// Round 16
// 839.027 us; speedup vs baseline: 1.1118x; 1.0429x over previous
//
#include <hip/hip_runtime.h>
#include <hip/hip_bf16.h>
#include <cstdint>
#include <cstddef>

#define ALPHA 0.1f
#define K_ITERS 10
#define NPART 8

typedef __attribute__((ext_vector_type(8))) short bf16x8;
typedef __attribute__((ext_vector_type(4))) float f32x4;
typedef __attribute__((ext_vector_type(4))) unsigned int u32x4;

#define U15INV (1.0f / 32767.0f)

__device__ __forceinline__ unsigned short f2bf(float f) {
    unsigned int u = __float_as_uint(f);
    u += 0x7fffu + ((u >> 16) & 1u);          // RNE
    return (unsigned short)(u >> 16);
}
__device__ __forceinline__ float bflo(unsigned int u) {
    return __uint_as_float(u << 16);
}
__device__ __forceinline__ float bfhi(unsigned int u) {
    return __uint_as_float(u & 0xffff0000u);
}
__device__ __forceinline__ unsigned int pack2(float a, float b) {
    return (unsigned int)f2bf(a) | ((unsigned int)f2bf(b) << 16);
}
__device__ __forceinline__ unsigned int u15q(float w) {   // w in [0,1]
    return (unsigned int)(w * 32767.0f + 0.5f);
}
__device__ __forceinline__ int xcd_id() {
    unsigned int x;
    asm volatile("s_getreg_b32 %0, hwreg(20, 0, 32)" : "=s"(x));   // HW_REG_XCC_ID (gfx950)
    return (int)(x & (NPART - 1));
}

// ---------------- helper kernels ----------------

// combined setup: zero cnt partitions, flag, and csr buffer
__global__ __launch_bounds__(256) void setup_k(int* cntp, unsigned int* cs, int* flag,
                                               int ncnt, int ncs) {
    int i = blockIdx.x * 256 + threadIdx.x;
    if (i == 0) *flag = 0;
    if (i < ncnt) cntp[i] = 0;
    if (i < ncs) cs[i] = 0;    // src=0, w=0 -> contributes 0
}

// Detect whether edge_index buffer is int64 (values in [0,N) when read as ll) or int32.
__global__ void detect_idx_k(const void* ei, int* flag, int E_, int N_) {
    int tid = threadIdx.x;
    const long long* p = (const long long*)ei;
    int bad = 0;
    int lim = (E_ < 4096) ? E_ : 4096;
    for (int i = tid; i < lim; i += 256) {
        long long v = p[i];
        if (v < 0 || v >= (long long)N_) bad = 1;
    }
    if (bad) atomicOr(flag, 1);   // 1 => buffer is int32
}

// fused weight prep:
// idx < F*D:  W1bT[n][k] = bf16( W1[k][n] * sigmoid_mask(xw[k]) )
// else:       W2bT[n][k] = bf16( W2[k][n] )
__global__ __launch_bounds__(256) void wprep_k(const float* W1, const float* xw, unsigned short* W1bT,
                                               const float* W2, unsigned short* W2bT,
                                               int F_, int D_, int C_) {
    int i = blockIdx.x * 256 + threadIdx.x;
    int n1 = F_ * D_;
    if (i < n1) {
        int k = i / D_, n = i % D_;
        float t = xw[k];
        float s = (fabsf(t) > 0.0f) ? 1.0f / (1.0f + expf(-t)) : 0.0f;
        W1bT[(size_t)n * F_ + k] = f2bf(W1[i] * s);
    } else if (i < n1 + D_ * C_) {
        int j = i - n1;
        int k = j / C_, n = j % C_;
        W2bT[(size_t)n * D_ + k] = f2bf(W2[j]);
    }
}

// ---------------- MERGED: fused MLP (blocks [0,gx)) + edge prep (blocks [gx,..)) ----------------
// The MLP chain (x,W1,W2 -> z0) and edge chain (ei,ew -> epack,cntp) share no
// data; co-scheduling them in one dispatch overlaps MFMA-bound gemm blocks
// with atomic-latency-bound prep blocks on disjoint HW resources.
__global__ __launch_bounds__(512) void mlp_prep_k(
        // gemm args
        const float* __restrict__ A, const unsigned short* __restrict__ BT,
        const float* __restrict__ b1, const unsigned short* __restrict__ W2bT,
        const float* __restrict__ b2, unsigned short* __restrict__ z0out,
        int M, int K, int Nn, int Cn, int gx,
        // prep args
        const void* __restrict__ ei, const float* __restrict__ ew,
        unsigned long long* __restrict__ epack, int* __restrict__ cntp,
        const int* __restrict__ flag, int E_, int N_) {
    __shared__ __align__(16) unsigned short SMEM[32768];   // 64KB union (gemm path only)

    if (blockIdx.x >= gx) {
        // ---------------- prep path: 512 edges per block ----------------
        int e = (blockIdx.x - gx) * 512 + threadIdx.x;
        if (e >= E_) return;
        int is32 = *flag;
        unsigned long long r, c;
        if (is32) {
            const int* p = (const int*)ei;
            r = (unsigned long long)(unsigned int)p[e];
            c = (unsigned long long)(unsigned int)p[(size_t)E_ + e];
        } else {
            const long long* p = (const long long*)ei;
            r = (unsigned long long)p[e];
            c = (unsigned long long)p[(size_t)E_ + e];
        }
        float t = ew[e];
        float wv = (fabsf(t) > 0.0f) ? 1.0f / (1.0f + expf(-t)) : 0.0f;
        unsigned long long part = (unsigned long long)xcd_id();
        unsigned long long rk = (unsigned long long)(unsigned int)
            __hip_atomic_fetch_add(&cntp[(size_t)part * N_ + (int)c], 1,
                                   __ATOMIC_RELAXED, __HIP_MEMORY_SCOPE_WORKGROUP);
        epack[e] = r | (c << 17) | ((unsigned long long)u15q(wv) << 34)
                     | (part << 49) | (rk << 52);
        return;
    }

    // ---------------- gemm path: fused z0 = relu(x@W1p+b1)@W2+b2 ----------------
    const int BK = 32;
    typedef unsigned short (*AslT)[4][128][8];
    typedef unsigned short (*BslT)[4][256][8];
    AslT Asl = (AslT)SMEM;
    BslT Bsl = (BslT)(SMEM + 8192);

    int tid = threadIdx.x;
    int row0 = blockIdx.x * 128;
    int wid = tid >> 6, lane = tid & 63;
    int wm = wid & 1, wn = wid >> 1;           // 2x4 wave grid, wave tile 64x64
    int lrow = lane & 15, kg = lane >> 4;

    f32x4 acc[4][4];
    #pragma unroll
    for (int i = 0; i < 4; ++i)
        #pragma unroll
        for (int j = 0; j < 4; ++j) acc[i][j] = (f32x4){0.f, 0.f, 0.f, 0.f};

    int ar = tid >> 2, akg = tid & 3;          // A: row, kgroup (8 floats)
    int agrow = row0 + ar;
    bool avalid = agrow < M;
    int bn_ = tid >> 1, bkh = (tid & 1) * 16;  // B: col, k-half (16 bf16)

    float fa[8];
    bf16x8 bv0, bv1;

    auto loadTile = [&](int k0) {
        if (avalid) {
            const f32x4* p = (const f32x4*)&A[(size_t)agrow * K + k0 + akg * 8];
            *(f32x4*)&fa[0] = p[0];
            *(f32x4*)&fa[4] = p[1];
        }
        const bf16x8* p = (const bf16x8*)&BT[(size_t)bn_ * K + k0 + bkh];
        bv0 = p[0]; bv1 = p[1];
    };
    auto stageTile = [&](int buf) {
        unsigned short av[8];
        #pragma unroll
        for (int q = 0; q < 8; ++q) av[q] = avalid ? f2bf(fa[q]) : (unsigned short)0;
        *(bf16x8*)&Asl[buf][akg][ar][0] = *(bf16x8*)&av[0];
        *(bf16x8*)&Bsl[buf][(bkh >> 3) + 0][bn_][0] = bv0;
        *(bf16x8*)&Bsl[buf][(bkh >> 3) + 1][bn_][0] = bv1;
    };

    int nsteps = K / BK;
    loadTile(0);
    stageTile(0);
    __syncthreads();

    int cur = 0;
    for (int step = 0; step < nsteps; ++step) {
        bool more = (step + 1) < nsteps;
        if (more) loadTile((step + 1) * BK);

        bf16x8 af[4], bfr[4];
        #pragma unroll
        for (int i = 0; i < 4; ++i)
            af[i] = *(bf16x8*)&Asl[cur][kg][wm * 64 + i * 16 + lrow][0];
        #pragma unroll
        for (int j = 0; j < 4; ++j)
            bfr[j] = *(bf16x8*)&Bsl[cur][kg][wn * 64 + j * 16 + lrow][0];
        #pragma unroll
        for (int i = 0; i < 4; ++i)
            #pragma unroll
            for (int j = 0; j < 4; ++j)
                acc[i][j] = __builtin_amdgcn_mfma_f32_16x16x32_bf16(af[i], bfr[j], acc[i][j], 0, 0, 0);

        if (more) stageTile(cur ^ 1);
        __syncthreads();
        cur ^= 1;
    }

    // ---- phase 2: h tile (bias+relu, bf16) into SMEM ----
    #pragma unroll
    for (int i = 0; i < 4; ++i) {
        #pragma unroll
        for (int j = 0; j < 4; ++j) {
            int k2 = wn * 64 + j * 16 + lrow;
            float bv = b1[k2];
            int base = ((k2 >> 5) * 4 + ((k2 >> 3) & 3)) * 1024 + (k2 & 7);
            #pragma unroll
            for (int r = 0; r < 4; ++r) {
                int row = wm * 64 + i * 16 + kg * 4 + r;
                float v = fmaxf(acc[i][j][r] + bv, 0.0f);
                SMEM[base + row * 8] = f2bf(v);
            }
        }
    }
    __syncthreads();

    // ---- phase 3: z0 slice ----
    f32x4 acc2[4];
    #pragma unroll
    for (int i = 0; i < 4; ++i) acc2[i] = (f32x4){0.f, 0.f, 0.f, 0.f};
    int col2 = wn * 16 + lrow;
    #pragma unroll
    for (int ch = 0; ch < 8; ++ch) {           // K2 = Nn = 256 -> 8 chunks of 32
        bf16x8 bfr2 = *(const bf16x8*)&W2bT[(size_t)col2 * Nn + ch * 32 + kg * 8];
        bf16x8 af2[4];
        #pragma unroll
        for (int i = 0; i < 4; ++i)
            af2[i] = *(bf16x8*)&SMEM[(ch * 4 + kg) * 1024 + (wm * 64 + i * 16 + lrow) * 8];
        #pragma unroll
        for (int i = 0; i < 4; ++i)
            acc2[i] = __builtin_amdgcn_mfma_f32_16x16x32_bf16(af2[i], bfr2, acc2[i], 0, 0, 0);
    }
    float bv2 = b2[col2];
    #pragma unroll
    for (int i = 0; i < 4; ++i) {
        #pragma unroll
        for (int r = 0; r < 4; ++r) {
            int grow = row0 + wm * 64 + i * 16 + kg * 4 + r;
            if (grow < M)
                z0out[(size_t)grow * Cn + col2] = f2bf(acc2[i][r] + bv2);
        }
    }
}

// per-node: prefix over NPART partition counts -> pofs; padded total -> cnt8
__global__ __launch_bounds__(256) void combine_k(const int* cntp, int* pofs, int* cnt8, int N_) {
    int i = blockIdx.x * 256 + threadIdx.x;
    if (i >= N_) return;
    int s = 0;
    #pragma unroll
    for (int p = 0; p < NPART; ++p) {
        size_t idx = (size_t)p * N_ + i;
        int v = cntp[idx];
        pofs[idx] = s;
        s += v;
    }
    cnt8[i] = (s + 7) & ~7;   // pad rows to multiple of 8
}

// hierarchical exclusive scan of cnt8 -> rowstart
__global__ __launch_bounds__(256) void scan1_k(const int* cnt, int* bsum, int N_) {
    __shared__ int sm[256];
    int t = threadIdx.x, i = blockIdx.x * 256 + t;
    sm[t] = (i < N_) ? cnt[i] : 0;
    __syncthreads();
    for (int off = 128; off; off >>= 1) {
        if (t < off) sm[t] += sm[t + off];
        __syncthreads();
    }
    if (t == 0) bsum[blockIdx.x] = sm[0];
}

__global__ __launch_bounds__(1024) void scan2_k(const int* bsum, int* boff, int nb) {
    __shared__ int sm[1024];
    int t = threadIdx.x;
    int v = (t < nb) ? bsum[t] : 0;
    sm[t] = v;
    __syncthreads();
    for (int off = 1; off < 1024; off <<= 1) {
        int x = (t >= off) ? sm[t - off] : 0;
        __syncthreads();
        sm[t] += x;
        __syncthreads();
    }
    if (t < nb) boff[t] = sm[t] - v;   // exclusive
}

__global__ __launch_bounds__(256) void scan3_k(const int* cnt, const int* boff, int* rowstart, int N_) {
    __shared__ int sm[256];
    int t = threadIdx.x, i = blockIdx.x * 256 + t;
    int v = (i < N_) ? cnt[i] : 0;
    sm[t] = v;
    __syncthreads();
    for (int off = 1; off < 256; off <<= 1) {
        int x = (t >= off) ? sm[t - off] : 0;
        __syncthreads();
        sm[t] += x;
        __syncthreads();
    }
    if (i < N_)  rowstart[i]  = boff[blockIdx.x] + sm[t] - v;
    if (i == N_ - 1) rowstart[N_] = boff[blockIdx.x] + sm[t];
}

// atomic-free CSR fill: pos = rowstart[c] + pofs[part][c] + rank
// csr entry: src:17 | unorm15(w) << 17
__global__ __launch_bounds__(256) void fill_csr_k(const unsigned long long* epack, const int* pofs,
                                                  const int* rowstart, unsigned int* cs,
                                                  int E_, int N_) {
    int e = blockIdx.x * 256 + threadIdx.x;
    if (e >= E_) return;
    unsigned long long v = epack[e];
    unsigned int r   = (unsigned int)(v & 0x1ffffu);
    int          c   = (int)((v >> 17) & 0x1ffffu);
    unsigned int w15 = (unsigned int)((v >> 34) & 0x7fffu);
    int         part = (int)((v >> 49) & 7u);
    int           rk = (int)(v >> 52);
    int pos = rowstart[c] + pofs[(size_t)part * N_ + c] + rk;
    cs[pos] = r | (w15 << 17);
}

// 32-lane group per node: deg = 1 + sum(w over row, pads are 0); dinv = rsqrt
__global__ __launch_bounds__(256) void deg_dinv_k(const unsigned int* __restrict__ cs,
                                                  const int* __restrict__ rowstart,
                                                  float* __restrict__ dinv, int N_) {
    int node = blockIdx.x * 8 + (threadIdx.x >> 5);
    int l = threadIdx.x & 31;
    if (node >= N_) return;
    int s = rowstart[node], e = rowstart[node + 1];
    float sum = 0.0f;
    for (int j = s + l; j < e; j += 32) sum += (float)(cs[j] >> 17) * U15INV;
    #pragma unroll
    for (int off = 16; off; off >>= 1) sum += __shfl_xor(sum, off, 64);
    float d = sum + 1.0f;   // self-loop
    if (l == 0) dinv[node] = (d > 0.0f) ? rsqrtf(fmaxf(d, 1e-12f)) : 0.0f;
}

// 32-lane group per node: rewrite w -> unorm15(dinv[src]*w*dinv[dst]) in place
__global__ __launch_bounds__(256) void norm_k(unsigned int* __restrict__ cs,
                                              const int* __restrict__ rowstart,
                                              const float* __restrict__ dinv, int N_) {
    int node = blockIdx.x * 8 + (threadIdx.x >> 5);
    int l = threadIdx.x & 31;
    if (node >= N_) return;
    int s = rowstart[node], e = rowstart[node + 1];
    float dc = dinv[node];
    for (int j = s + l; j < e; j += 32) {
        unsigned int v = cs[j];
        unsigned int src = v & 0x1ffffu;
        float w = (float)(v >> 17) * U15INV;
        float nm = dinv[src] * w * dc;
        cs[j] = src | (u15q(nm) << 17);
    }
}

// ---------------- propagation: 8 lanes per node, 8 nodes per wave ----------------
template<bool LAST>
__global__ __launch_bounds__(256) void prop8_k(const unsigned short* __restrict__ z,
                                               const unsigned short* __restrict__ z0,
                                               const int* __restrict__ rowstart,
                                               const unsigned int* __restrict__ cs,
                                               const float* __restrict__ dinv,
                                               unsigned short* __restrict__ znew,
                                               float* __restrict__ out, int N_) {
    int node = blockIdx.x * 32 + (threadIdx.x >> 3);
    int l = threadIdx.x & 7;
    if (node >= N_) return;
    int s = rowstart[node], e = rowstart[node + 1];   // multiples of 8
    float d = dinv[node];
    size_t ro = (size_t)node * 64 + l * 8;
    u32x4 zs = *(const u32x4*)&z[ro];
    float dd = d * d;
    float a[8];
    a[0] = dd * bflo(zs.x); a[1] = dd * bfhi(zs.x);
    a[2] = dd * bflo(zs.y); a[3] = dd * bfhi(zs.y);
    a[4] = dd * bflo(zs.z); a[5] = dd * bfhi(zs.z);
    a[6] = dd * bflo(zs.w); a[7] = dd * bfhi(zs.w);

    for (int j = s; j < e; j += 8) {
        u32x4 p0 = __builtin_nontemporal_load((const u32x4*)&cs[j]);
        u32x4 p1 = __builtin_nontemporal_load((const u32x4*)&cs[j + 4]);
        unsigned int pe[8] = { p0.x, p0.y, p0.z, p0.w, p1.x, p1.y, p1.z, p1.w };
        u32x4 g[8];
        #pragma unroll
        for (int q = 0; q < 8; ++q)
            g[q] = *(const u32x4*)&z[(size_t)(pe[q] & 0x1ffffu) * 64 + l * 8];
        #pragma unroll
        for (int q = 0; q < 8; ++q) {
            float w = (float)(pe[q] >> 17) * U15INV;
            a[0] += w * bflo(g[q].x); a[1] += w * bfhi(g[q].x);
            a[2] += w * bflo(g[q].y); a[3] += w * bfhi(g[q].y);
            a[4] += w * bflo(g[q].z); a[5] += w * bfhi(g[q].z);
            a[6] += w * bflo(g[q].w); a[7] += w * bfhi(g[q].w);
        }
    }

    u32x4 z0v = __builtin_nontemporal_load((const u32x4*)&z0[ro]);
    float v[8];
    float z0f[8] = { bflo(z0v.x), bfhi(z0v.x), bflo(z0v.y), bfhi(z0v.y),
                     bflo(z0v.z), bfhi(z0v.z), bflo(z0v.w), bfhi(z0v.w) };
    #pragma unroll
    for (int q = 0; q < 8; ++q) v[q] = (1.0f - ALPHA) * a[q] + ALPHA * z0f[q];

    if (!LAST) {
        u32x4 o;
        o.x = pack2(v[0], v[1]); o.y = pack2(v[2], v[3]);
        o.z = pack2(v[4], v[5]); o.w = pack2(v[6], v[7]);
        *(u32x4*)&znew[ro] = o;      // normal store: let z dwell in L2
    } else {
        float m = v[0];
        #pragma unroll
        for (int q = 1; q < 8; ++q) m = fmaxf(m, v[q]);
        #pragma unroll
        for (int off = 1; off < 8; off <<= 1) m = fmaxf(m, __shfl_xor(m, off, 64));
        float sum = 0.0f;
        #pragma unroll
        for (int q = 0; q < 8; ++q) sum += expf(v[q] - m);
        #pragma unroll
        for (int off = 1; off < 8; off <<= 1) sum += __shfl_xor(sum, off, 64);
        float lg = logf(sum);
        float4 o0 = make_float4(v[0] - m - lg, v[1] - m - lg, v[2] - m - lg, v[3] - m - lg);
        float4 o1 = make_float4(v[4] - m - lg, v[5] - m - lg, v[6] - m - lg, v[7] - m - lg);
        *(float4*)&out[ro] = o0;
        *(float4*)&out[ro + 4] = o1;
    }
}

// ---------------- launcher ----------------

extern "C" void kernel_launch(void* const* d_in, const int* in_sizes, int n_in,
                              void* d_out, int out_size, void* d_ws, size_t ws_size,
                              hipStream_t stream) {
    const float* x   = (const float*)d_in[0];
    const void*  ei  = d_in[1];
    const float* ew  = (const float*)d_in[2];
    const float* xw  = (const float*)d_in[3];
    const float* W1  = (const float*)d_in[4];
    const float* b1  = (const float*)d_in[5];
    const float* W2  = (const float*)d_in[6];
    const float* b2  = (const float*)d_in[7];

    const int F_ = in_sizes[3];          // 512
    const int N_ = in_sizes[0] / F_;     // 100000
    const int E_ = in_sizes[2];          // 3200000
    const int D_ = in_sizes[5];          // 256
    const int C_ = in_sizes[7];          // 64

    const int E8 = E_ + 7 * N_;          // upper bound on padded edge count

    char* base = (char*)d_ws;
    size_t off = 0;
    auto take = [&](size_t bytes) -> void* {
        void* p = base + off;
        off += (bytes + 255) & ~(size_t)255;
        return p;
    };
    unsigned long long* epack = (unsigned long long*)take((size_t)E_ * 8);
    unsigned int* cs = (unsigned int*)take((size_t)E8 * 4);
    int*   cntp     = (int*)  take((size_t)NPART * N_ * 4);
    int*   pofs     = (int*)  take((size_t)NPART * N_ * 4);
    int*   cnt8     = (int*)  take((size_t)N_ * 4);
    float* dinv     = (float*)take((size_t)N_ * 4);
    int*   rowstart = (int*)  take((size_t)(N_ + 1) * 4);
    int*   flag     = (int*)  take(256);
    int*   bsum     = (int*)  take(4096 * 4);
    int*   boff     = (int*)  take(4096 * 4);
    unsigned short* W1bT = (unsigned short*)take((size_t)F_ * D_ * 2);
    unsigned short* W2bT = (unsigned short*)take((size_t)D_ * C_ * 2);
    unsigned short* z0b  = (unsigned short*)take((size_t)N_ * C_ * 2);
    unsigned short* za   = (unsigned short*)take((size_t)N_ * C_ * 2);
    unsigned short* zb   = (unsigned short*)take((size_t)N_ * C_ * 2);

    (void)ws_size; (void)n_in; (void)out_size;

    int nblk = (N_ + 255) / 256;
    int eblk = (E_ + 255) / 256;
    int ncnt = NPART * N_;
    int setup_blk = ((ncnt > E8 ? ncnt : E8) + 255) / 256;

    setup_k<<<setup_blk, 256, 0, stream>>>(cntp, cs, flag, ncnt, E8);
    detect_idx_k<<<1, 256, 0, stream>>>(ei, flag, E_, N_);
    wprep_k<<<(F_ * D_ + D_ * C_ + 255) / 256, 256, 0, stream>>>(W1, xw, W1bT, W2, W2bT, F_, D_, C_);

    // MERGED: fused MLP (first gx blocks) + edge prep (remaining blocks)
    int gx = (N_ + 127) / 128;
    int eblk512 = (E_ + 511) / 512;
    mlp_prep_k<<<gx + eblk512, 512, 0, stream>>>(
        x, W1bT, b1, W2bT, b2, z0b, N_, F_, D_, C_, gx,
        ei, ew, epack, cntp, flag, E_, N_);

    combine_k<<<nblk, 256, 0, stream>>>(cntp, pofs, cnt8, N_);
    scan1_k<<<nblk, 256, 0, stream>>>(cnt8, bsum, N_);
    scan2_k<<<1, 1024, 0, stream>>>(bsum, boff, nblk);
    scan3_k<<<nblk, 256, 0, stream>>>(cnt8, boff, rowstart, N_);
    fill_csr_k<<<eblk, 256, 0, stream>>>(epack, pofs, rowstart, cs, E_, N_);
    int gblk8 = (N_ + 7) / 8;
    deg_dinv_k<<<gblk8, 256, 0, stream>>>(cs, rowstart, dinv, N_);
    norm_k<<<gblk8, 256, 0, stream>>>(cs, rowstart, dinv, N_);

    int pblk = (N_ + 31) / 32;
    const unsigned short* cur = z0b;
    unsigned short* bufs[2] = { za, zb };
    for (int it = 0; it < K_ITERS - 1; ++it) {
        unsigned short* dst = bufs[it & 1];
        prop8_k<false><<<pblk, 256, 0, stream>>>(cur, z0b, rowstart, cs, dinv, dst, nullptr, N_);
        cur = dst;
    }
    prop8_k<true><<<pblk, 256, 0, stream>>>(cur, z0b, rowstart, cs, dinv, nullptr, (float*)d_out, N_);
}